// Round 14
// baseline (110.458 us; speedup 1.0000x reference)
//
#include <hip/hip_runtime.h>
#include <hip/hip_bf16.h>

#define B_SZ 4
#define N_SZ 512
#define IN_DIM 128
#define NH 8
#define HD 16
#define SLOPE 0.2f

typedef float v2f __attribute__((ext_vector_type(2)));

// ws layout (floats): gl, gr
#define WS_GL 0
#define WS_GR (NH * B_SZ * N_SZ * HD)                    // 262144
#define WS_TOT (2 * WS_GR)

// ---------------- proj as register-tiled GEMM (unchanged from R11) ----------------
#define PM 32
#define PKC 64
#define AT_S 38
#define BT_S 68

__global__ __launch_bounds__(256) void proj_gemm(
    const float* __restrict__ hin, const float* __restrict__ Wl,
    const float* __restrict__ Wr, float* __restrict__ gl, float* __restrict__ gr)
{
    __shared__ float At[PKC * AT_S];
    __shared__ float Bs[PKC * BT_S];

    int rt = blockIdx.x >> 2;
    int ct = blockIdx.x & 3;
    int side = ct >> 1;
    int headbase = (ct & 1) * 4;
    const float* Wsrc = side ? Wr : Wl;
    int rowbase = rt * PM;

    int t = threadIdx.x;
    int ty = t >> 4;
    int tx = t & 15;

    float acc[2][4] = {{0.f,0.f,0.f,0.f},{0.f,0.f,0.f,0.f}};

    for (int kc = 0; kc < IN_DIM; kc += PKC) {
        __syncthreads();
#pragma unroll
        for (int it = 0; it < 2; ++it) {
            int task = it * 256 + t;
            int r = task >> 4, kq = task & 15;
            float4 v = *(const float4*)&hin[(size_t)(rowbase + r) * IN_DIM + kc + kq * 4];
            At[(kq * 4 + 0) * AT_S + r] = v.x;
            At[(kq * 4 + 1) * AT_S + r] = v.y;
            At[(kq * 4 + 2) * AT_S + r] = v.z;
            At[(kq * 4 + 3) * AT_S + r] = v.w;
        }
#pragma unroll
        for (int it = 0; it < 4; ++it) {
            int task = it * 256 + t;
            int k = task >> 4, cc4 = task & 15;
            int head = headbase + (cc4 >> 2);
            int dq = (cc4 & 3) * 4;
            float4 v = *(const float4*)&Wsrc[head * (IN_DIM * HD) + (kc + k) * HD + dq];
            *(float4*)&Bs[k * BT_S + cc4 * 4] = v;
        }
        __syncthreads();

#pragma unroll 16
        for (int k = 0; k < PKC; ++k) {
            float2 a = *(const float2*)&At[k * AT_S + ty * 2];
            float4 b = *(const float4*)&Bs[k * BT_S + tx * 4];
            acc[0][0] = fmaf(a.x, b.x, acc[0][0]);
            acc[0][1] = fmaf(a.x, b.y, acc[0][1]);
            acc[0][2] = fmaf(a.x, b.z, acc[0][2]);
            acc[0][3] = fmaf(a.x, b.w, acc[0][3]);
            acc[1][0] = fmaf(a.y, b.x, acc[1][0]);
            acc[1][1] = fmaf(a.y, b.y, acc[1][1]);
            acc[1][2] = fmaf(a.y, b.z, acc[1][2]);
            acc[1][3] = fmaf(a.y, b.w, acc[1][3]);
        }
    }

    int head = headbase + (tx >> 2);
    int d4 = (tx & 3) * 4;
    float* g = side ? gr : gl;
#pragma unroll
    for (int r = 0; r < 2; ++r) {
        int row = rowbase + ty * 2 + r;
        int b = row >> 9, i = row & (N_SZ - 1);
        float4 v = {acc[r][0], acc[r][1], acc[r][2], acc[r][3]};
        *(float4*)&g[((size_t)(head * B_SZ + b) * N_SZ + i) * HD + d4] = v;
    }
}

// ---------------- attn: barrier-free, one wave per (hb, i-pair) ----------------
// score (minus per-row const, softmax-invariant) = 0.6*(a.gr_j) + 0.4*sum_d a_d|gl_id+gr_jd|
__global__ __launch_bounds__(256) void attn_wave(
    const float* __restrict__ gl, const float* __restrict__ gr,
    const float* __restrict__ Wak, const unsigned char* __restrict__ mask,
    float* __restrict__ out)
{
    int bid = blockIdx.x;
    int hb = bid >> 6;                 // head*4 + b
    int head = hb >> 2, b = hb & 3;
    int t = threadIdx.x;
    int wv = t >> 6;                   // wave 0..3
    int lane = t & 63;
    int jh = lane >> 1;                // 0..31 j-lane
    int h = lane & 1;                  // half: dims h*8 .. h*8+7

    int pair = (bid & 63) * 4 + wv;    // 0..255
    int i0 = pair * 2;

    const float* grb = gr + (size_t)hb * (N_SZ * HD);
    const float* gl0 = gl + ((size_t)hb * N_SZ + i0) * HD;
    const float* ap = Wak + head * HD;

    float a[8], w0[8], w1[8];
    {
        float4 a0 = *(const float4*)(ap + h * 8);
        float4 a1 = *(const float4*)(ap + h * 8 + 4);
        float4 u0 = *(const float4*)(gl0 + h * 8);
        float4 u1 = *(const float4*)(gl0 + h * 8 + 4);
        float4 v0 = *(const float4*)(gl0 + HD + h * 8);
        float4 v1 = *(const float4*)(gl0 + HD + h * 8 + 4);
        a[0]=a0.x; a[1]=a0.y; a[2]=a0.z; a[3]=a0.w;
        a[4]=a1.x; a[5]=a1.y; a[6]=a1.z; a[7]=a1.w;
        w0[0]=u0.x; w0[1]=u0.y; w0[2]=u0.z; w0[3]=u0.w;
        w0[4]=u1.x; w0[5]=u1.y; w0[6]=u1.z; w0[7]=u1.w;
        w1[0]=v0.x; w1[1]=v0.y; w1[2]=v0.z; w1[3]=v0.w;
        w1[4]=v1.x; w1[5]=v1.y; w1[6]=v1.z; w1[7]=v1.w;
    }

    const unsigned char* m0p = mask + ((size_t)(b * N_SZ + i0)) * N_SZ;
    const unsigned char* m1p = m0p + N_SZ;

    float o0[8], o1[8];
#pragma unroll
    for (int k = 0; k < 8; ++k) { o0[k] = 0.f; o1[k] = 0.f; }
    float l0 = 0.f, l1 = 0.f;

#pragma unroll 4
    for (int it = 0; it < N_SZ / 32; ++it) {
        int j = it * 32 + jh;
        const float* src = grb + it * 512 + lane * 8;
        float4 ga = *(const float4*)src;
        float4 gb = *(const float4*)(src + 4);
        float g[8] = {ga.x, ga.y, ga.z, ga.w, gb.x, gb.y, gb.z, gb.w};

        float u = 0.f, s0p = 0.f, s1p = 0.f;
#pragma unroll
        for (int k = 0; k < 8; ++k) {
            u = fmaf(a[k], g[k], u);
            s0p = fmaf(a[k], fabsf(w0[k] + g[k]), s0p);
            s1p = fmaf(a[k], fabsf(w1[k] + g[k]), s1p);
        }
        float u06 = 0.6f * u;
        float s0 = fmaf(0.4f, s0p, u06);
        float s1 = fmaf(0.4f, s1p, u06);
        s0 += __shfl_xor(s0, 1, 64);
        s1 += __shfl_xor(s1, 1, 64);

        unsigned char mm0 = m0p[j];
        unsigned char mm1 = m1p[j];
        s0 = mm0 ? -1e30f : fminf(s0, 80.f);
        s1 = mm1 ? -1e30f : fminf(s1, 80.f);

        float p0 = __expf(s0);
        float p1 = __expf(s1);
        l0 += p0; l1 += p1;
#pragma unroll
        for (int k = 0; k < 8; ++k) {
            o0[k] = fmaf(p0, g[k], o0[k]);
            o1[k] = fmaf(p1, g[k], o1[k]);
        }
    }

#pragma unroll
    for (int off = 2; off < 64; off <<= 1) {
        l0 += __shfl_xor(l0, off, 64);
        l1 += __shfl_xor(l1, off, 64);
#pragma unroll
        for (int k = 0; k < 8; ++k) {
            o0[k] += __shfl_xor(o0[k], off, 64);
            o1[k] += __shfl_xor(o1[k], off, 64);
        }
    }

    if (lane < 4) {
        int r = lane >> 1;
        float li = r ? l1 : l0;
        float inv = 1.f / li;
        const float* oo = r ? o1 : o0;
        float res[8];
#pragma unroll
        for (int k = 0; k < 8; ++k)
            res[k] = fmaxf(oo[k] * inv, 0.f);
        float* op = out + ((size_t)(b * N_SZ + i0 + r)) * (NH * HD)
                        + head * HD + (lane & 1) * 8;
        *(float4*)op = *(float4*)res;
        *(float4*)(op + 4) = *(float4*)(res + 4);
    }
}

// ---------------- fallback: fused kernel (no workspace) ----------------
__global__ __launch_bounds__(512) void gatv2_fused(
    const float* __restrict__ hin, const unsigned char* __restrict__ mask,
    const float* __restrict__ Wl, const float* __restrict__ Wr,
    const float* __restrict__ Wak, float* __restrict__ out)
{
    __shared__ float wrs[IN_DIM * HD];
    __shared__ float hsh[32][IN_DIM + 1];
    __shared__ float grs[N_SZ * 18];
    __shared__ float gls[32][HD];

    int bid = blockIdx.x;
    int itile = bid & 15;
    int hb = bid >> 4;
    int head = hb >> 2, b = hb & 3;
    int t = threadIdx.x;

    int jl = t >> 4;
    int d  = t & 15;

    for (int idx = t; idx < IN_DIM * HD; idx += 512)
        wrs[idx] = Wr[head * IN_DIM * HD + idx];

    const float* hb_base = hin + (size_t)b * N_SZ * IN_DIM;
    const float* wlcol = Wl + head * IN_DIM * HD + d;

    for (int c = 0; c < N_SZ / 32; ++c) {
        __syncthreads();
        const float* hc = hb_base + (size_t)c * 32 * IN_DIM;
        for (int idx = t; idx < 32 * IN_DIM; idx += 512)
            hsh[idx >> 7][idx & 127] = hc[idx];
        __syncthreads();

        float acc = 0.f;
#pragma unroll 16
        for (int k = 0; k < IN_DIM; ++k)
            acc = fmaf(hsh[jl][k], wrs[k * HD + d], acc);
        grs[(c * 32 + jl) * 18 + d] = acc;

        if (c == itile) {
            float accl = 0.f;
#pragma unroll 16
            for (int k = 0; k < IN_DIM; ++k)
                accl = fmaf(hsh[jl][k], wlcol[k * HD], accl);
            gls[jl][d] = accl;
        }
    }
    __syncthreads();

    int il = jl, jt = d;
    int i = itile * 32 + il;

    float glv[HD], avv[HD];
#pragma unroll
    for (int dd = 0; dd < HD; ++dd) glv[dd] = gls[il][dd];
    const float* ap = Wak + head * HD;
#pragma unroll
    for (int dd = 0; dd < HD; ++dd) avv[dd] = ap[dd];

    const unsigned char* mrow = mask + ((size_t)(b * N_SZ + i)) * N_SZ;

    float m = -1e30f, l = 0.f;
    float o[HD];
#pragma unroll
    for (int dd = 0; dd < HD; ++dd) o[dd] = 0.f;

    for (int jj = 0; jj < N_SZ / 16; ++jj) {
        int j = jj * 16 + jt;
        const float* r = &grs[j * 18];
        float gj[HD];
#pragma unroll
        for (int e = 0; e < HD / 2; ++e) {
            float2 v = *(const float2*)(r + 2 * e);
            gj[2 * e] = v.x; gj[2 * e + 1] = v.y;
        }

        float s = 0.f;
#pragma unroll
        for (int dd = 0; dd < HD; ++dd) {
            float x = glv[dd] + gj[dd];
            float lr = fmaxf(x, SLOPE * x);
            s = fmaf(avv[dd], lr, s);
        }
        if (mrow[j]) s = -1e30f;

        float mn = fmaxf(m, s);
        float cc = __expf(m - mn);
        float p = __expf(s - mn);
        l = fmaf(l, cc, p);
#pragma unroll
        for (int dd = 0; dd < HD; ++dd)
            o[dd] = fmaf(o[dd], cc, p * gj[dd]);
        m = mn;
    }

#pragma unroll
    for (int off = 1; off < 16; off <<= 1) {
        float mo = __shfl_xor(m, off, 64);
        float lo = __shfl_xor(l, off, 64);
        float mn = fmaxf(m, mo);
        float c1 = __expf(m - mn), c2 = __expf(mo - mn);
        l = l * c1 + lo * c2;
#pragma unroll
        for (int dd = 0; dd < HD; ++dd)
            o[dd] = o[dd] * c1 + __shfl_xor(o[dd], off, 64) * c2;
        m = mn;
    }

    if (jt == 0) {
        float inv = 1.f / l;
        float res[HD];
#pragma unroll
        for (int dd = 0; dd < HD; ++dd)
            res[dd] = fmaxf(o[dd] * inv, 0.f);
        float* op = out + ((size_t)(b * N_SZ + i)) * (NH * HD) + head * HD;
#pragma unroll
        for (int e = 0; e < HD / 4; ++e)
            *(float4*)(op + 4 * e) = *(float4*)(res + 4 * e);
    }
}

extern "C" void kernel_launch(void* const* d_in, const int* in_sizes, int n_in,
                              void* d_out, int out_size, void* d_ws, size_t ws_size,
                              hipStream_t stream) {
    const float* hin = (const float*)d_in[0];
    const unsigned char* mask = (const unsigned char*)d_in[1];
    const float* Wl = (const float*)d_in[2];
    const float* Wr = (const float*)d_in[3];
    const float* Wak = (const float*)d_in[4];
    float* out = (float*)d_out;
    (void)in_sizes; (void)n_in; (void)out_size;

    const size_t need = (size_t)WS_TOT * sizeof(float);   // 2 MB

    if (ws_size >= need && d_ws != nullptr) {
        float* ws = (float*)d_ws;
        float* gl = ws + WS_GL;
        float* gr = ws + WS_GR;
        proj_gemm<<<(B_SZ * N_SZ / PM) * 4, 256, 0, stream>>>(hin, Wl, Wr, gl, gr);
        // DIAGNOSTIC round: attn launched twice (idempotent — recomputes and
        // rewrites identical output). dur_us delta vs round 13 = attn's true cost.
        attn_wave<<<NH * B_SZ * 64, 256, 0, stream>>>(gl, gr, Wak, mask, out);
        attn_wave<<<NH * B_SZ * 64, 256, 0, stream>>>(gl, gr, Wak, mask, out);
    } else {
        gatv2_fused<<<NH * B_SZ * (N_SZ / 32), 512, 0, stream>>>(
            hin, mask, Wl, Wr, Wak, out);
    }
}

// Round 15
// 97.129 us; speedup vs baseline: 1.1372x; 1.1372x over previous
//
#include <hip/hip_runtime.h>
#include <hip/hip_bf16.h>

#define B_SZ 4
#define N_SZ 512
#define IN_DIM 128
#define NH 8
#define HD 16
#define SLOPE 0.2f

typedef float v2f __attribute__((ext_vector_type(2)));

// ws layout (floats): gl, gr
#define WS_GL 0
#define WS_GR (NH * B_SZ * N_SZ * HD)                    // 262144
#define WS_TOT (2 * WS_GR)

// ---------------- proj as register-tiled GEMM (unchanged from R11) ----------------
#define PM 32
#define PKC 64
#define AT_S 38
#define BT_S 68

__global__ __launch_bounds__(256) void proj_gemm(
    const float* __restrict__ hin, const float* __restrict__ Wl,
    const float* __restrict__ Wr, float* __restrict__ gl, float* __restrict__ gr)
{
    __shared__ float At[PKC * AT_S];
    __shared__ float Bs[PKC * BT_S];

    int rt = blockIdx.x >> 2;
    int ct = blockIdx.x & 3;
    int side = ct >> 1;
    int headbase = (ct & 1) * 4;
    const float* Wsrc = side ? Wr : Wl;
    int rowbase = rt * PM;

    int t = threadIdx.x;
    int ty = t >> 4;
    int tx = t & 15;

    float acc[2][4] = {{0.f,0.f,0.f,0.f},{0.f,0.f,0.f,0.f}};

    for (int kc = 0; kc < IN_DIM; kc += PKC) {
        __syncthreads();
#pragma unroll
        for (int it = 0; it < 2; ++it) {
            int task = it * 256 + t;
            int r = task >> 4, kq = task & 15;
            float4 v = *(const float4*)&hin[(size_t)(rowbase + r) * IN_DIM + kc + kq * 4];
            At[(kq * 4 + 0) * AT_S + r] = v.x;
            At[(kq * 4 + 1) * AT_S + r] = v.y;
            At[(kq * 4 + 2) * AT_S + r] = v.z;
            At[(kq * 4 + 3) * AT_S + r] = v.w;
        }
#pragma unroll
        for (int it = 0; it < 4; ++it) {
            int task = it * 256 + t;
            int k = task >> 4, cc4 = task & 15;
            int head = headbase + (cc4 >> 2);
            int dq = (cc4 & 3) * 4;
            float4 v = *(const float4*)&Wsrc[head * (IN_DIM * HD) + (kc + k) * HD + dq];
            *(float4*)&Bs[k * BT_S + cc4 * 4] = v;
        }
        __syncthreads();

#pragma unroll 16
        for (int k = 0; k < PKC; ++k) {
            float2 a = *(const float2*)&At[k * AT_S + ty * 2];
            float4 b = *(const float4*)&Bs[k * BT_S + tx * 4];
            acc[0][0] = fmaf(a.x, b.x, acc[0][0]);
            acc[0][1] = fmaf(a.x, b.y, acc[0][1]);
            acc[0][2] = fmaf(a.x, b.z, acc[0][2]);
            acc[0][3] = fmaf(a.x, b.w, acc[0][3]);
            acc[1][0] = fmaf(a.y, b.x, acc[1][0]);
            acc[1][1] = fmaf(a.y, b.y, acc[1][1]);
            acc[1][2] = fmaf(a.y, b.z, acc[1][2]);
            acc[1][3] = fmaf(a.y, b.w, acc[1][3]);
        }
    }

    int head = headbase + (tx >> 2);
    int d4 = (tx & 3) * 4;
    float* g = side ? gr : gl;
#pragma unroll
    for (int r = 0; r < 2; ++r) {
        int row = rowbase + ty * 2 + r;
        int b = row >> 9, i = row & (N_SZ - 1);
        float4 v = {acc[r][0], acc[r][1], acc[r][2], acc[r][3]};
        *(float4*)&g[((size_t)(head * B_SZ + b) * N_SZ + i) * HD + d4] = v;
    }
}

// ---------------- attn: barrier-free, one wave per (hb, 4 i-rows) ----------------
// score (minus per-row const, softmax-invariant) = 0.6*(a.gr_j) + 0.4*sum_d a_d|gl_id+gr_jd|
// lane = (jh 0..31, h 0..1); wave covers 32 j's/iter x 16 iters; 4 rows share g loads.
__global__ __launch_bounds__(256) void attn_wave(
    const float* __restrict__ gl, const float* __restrict__ gr,
    const float* __restrict__ Wak, const unsigned char* __restrict__ mask,
    float* __restrict__ out)
{
    int bid = blockIdx.x;              // 1024 blocks
    int hb = bid >> 5;                 // head*4 + b
    int head = hb >> 2, b = hb & 3;
    int t = threadIdx.x;
    int wv = t >> 6;                   // wave 0..3
    int lane = t & 63;
    int jh = lane >> 1;                // 0..31 j-lane
    int h = lane & 1;                  // half: dims h*8 .. h*8+7
    int i0 = ((bid & 31) * 4 + wv) * 4;   // 0,4,...,508

    const float* grb = gr + (size_t)hb * (N_SZ * HD);
    const float* gl0 = gl + ((size_t)hb * N_SZ + i0) * HD;
    const float* ap = Wak + head * HD;

    float a[8];
    {
        float4 a0 = *(const float4*)(ap + h * 8);
        float4 a1 = *(const float4*)(ap + h * 8 + 4);
        a[0]=a0.x; a[1]=a0.y; a[2]=a0.z; a[3]=a0.w;
        a[4]=a1.x; a[5]=a1.y; a[6]=a1.z; a[7]=a1.w;
    }

    v2f w[4][4], o[4][4];
#pragma unroll
    for (int r = 0; r < 4; ++r) {
        float4 u0 = *(const float4*)(gl0 + r * HD + h * 8);
        float4 u1 = *(const float4*)(gl0 + r * HD + h * 8 + 4);
        w[r][0] = (v2f){u0.x, u0.y}; w[r][1] = (v2f){u0.z, u0.w};
        w[r][2] = (v2f){u1.x, u1.y}; w[r][3] = (v2f){u1.z, u1.w};
#pragma unroll
        for (int e = 0; e < 4; ++e) o[r][e] = (v2f){0.f, 0.f};
    }

    const unsigned char* mrow = mask + ((size_t)(b * N_SZ + i0)) * N_SZ;
    float l[4] = {0.f, 0.f, 0.f, 0.f};

#pragma unroll 2
    for (int it = 0; it < N_SZ / 32; ++it) {
        int j = it * 32 + jh;
        const float* src = grb + it * 512 + lane * 8;   // (j*16 + h*8)
        float4 ga = *(const float4*)src;
        float4 gb = *(const float4*)(src + 4);
        // mask bytes for the 4 rows: independent, issued early
        unsigned char mm0 = mrow[j];
        unsigned char mm1 = mrow[N_SZ + j];
        unsigned char mm2 = mrow[2 * N_SZ + j];
        unsigned char mm3 = mrow[3 * N_SZ + j];
        v2f g[4] = {(v2f){ga.x, ga.y}, (v2f){ga.z, ga.w},
                    (v2f){gb.x, gb.y}, (v2f){gb.z, gb.w}};

        // shared term: u = a . g (this half)
        float u = 0.f;
#pragma unroll
        for (int e = 0; e < 4; ++e) {
            u = fmaf(a[2 * e],     g[e].x, u);
            u = fmaf(a[2 * e + 1], g[e].y, u);
        }
        float u06 = 0.6f * u;

        float s[4];
#pragma unroll
        for (int r = 0; r < 4; ++r) {
            float sp0 = 0.f, sp1 = 0.f;
#pragma unroll
            for (int e = 0; e < 4; ++e) {
                v2f x = w[r][e] + g[e];              // v_pk_add_f32
                sp0 = fmaf(a[2 * e],     fabsf(x.x), sp0);
                sp1 = fmaf(a[2 * e + 1], fabsf(x.y), sp1);
            }
            s[r] = fmaf(0.4f, sp0 + sp1, u06);
        }
        // combine the two half-row partials (lane ^ 1)
#pragma unroll
        for (int r = 0; r < 4; ++r)
            s[r] += __shfl_xor(s[r], 1, 64);

        s[0] = mm0 ? -1e30f : fminf(s[0], 80.f);
        s[1] = mm1 ? -1e30f : fminf(s[1], 80.f);
        s[2] = mm2 ? -1e30f : fminf(s[2], 80.f);
        s[3] = mm3 ? -1e30f : fminf(s[3], 80.f);

#pragma unroll
        for (int r = 0; r < 4; ++r) {
            float p = __expf(s[r]);
            l[r] += p;
            v2f pv = (v2f){p, p};
#pragma unroll
            for (int e = 0; e < 4; ++e)
                o[r][e] += pv * g[e];                // v_pk_fma_f32
        }
    }

    // merge across the 32 j-lanes (bits 1..5; NOT bit0 = h)
#pragma unroll
    for (int off = 2; off < 64; off <<= 1) {
#pragma unroll
        for (int r = 0; r < 4; ++r) {
            l[r] += __shfl_xor(l[r], off, 64);
#pragma unroll
            for (int e = 0; e < 4; ++e) {
                v2f q;
                q.x = __shfl_xor(o[r][e].x, off, 64);
                q.y = __shfl_xor(o[r][e].y, off, 64);
                o[r][e] += q;
            }
        }
    }

    // writers: lanes 0..7 -> (row = lane>>1, half = lane&1 == own h)
    if (lane < 8) {
        int r = lane >> 1;
        float inv = 1.f / l[r];
        float res[8];
#pragma unroll
        for (int e = 0; e < 4; ++e) {
            res[2 * e]     = fmaxf(o[r][e].x * inv, 0.f);
            res[2 * e + 1] = fmaxf(o[r][e].y * inv, 0.f);
        }
        float* op = out + ((size_t)(b * N_SZ + i0 + r)) * (NH * HD)
                        + head * HD + h * 8;
        *(float4*)op = *(float4*)res;
        *(float4*)(op + 4) = *(float4*)(res + 4);
    }
}

// ---------------- fallback: fused kernel (no workspace) ----------------
__global__ __launch_bounds__(512) void gatv2_fused(
    const float* __restrict__ hin, const unsigned char* __restrict__ mask,
    const float* __restrict__ Wl, const float* __restrict__ Wr,
    const float* __restrict__ Wak, float* __restrict__ out)
{
    __shared__ float wrs[IN_DIM * HD];
    __shared__ float hsh[32][IN_DIM + 1];
    __shared__ float grs[N_SZ * 18];
    __shared__ float gls[32][HD];

    int bid = blockIdx.x;
    int itile = bid & 15;
    int hb = bid >> 4;
    int head = hb >> 2, b = hb & 3;
    int t = threadIdx.x;

    int jl = t >> 4;
    int d  = t & 15;

    for (int idx = t; idx < IN_DIM * HD; idx += 512)
        wrs[idx] = Wr[head * IN_DIM * HD + idx];

    const float* hb_base = hin + (size_t)b * N_SZ * IN_DIM;
    const float* wlcol = Wl + head * IN_DIM * HD + d;

    for (int c = 0; c < N_SZ / 32; ++c) {
        __syncthreads();
        const float* hc = hb_base + (size_t)c * 32 * IN_DIM;
        for (int idx = t; idx < 32 * IN_DIM; idx += 512)
            hsh[idx >> 7][idx & 127] = hc[idx];
        __syncthreads();

        float acc = 0.f;
#pragma unroll 16
        for (int k = 0; k < IN_DIM; ++k)
            acc = fmaf(hsh[jl][k], wrs[k * HD + d], acc);
        grs[(c * 32 + jl) * 18 + d] = acc;

        if (c == itile) {
            float accl = 0.f;
#pragma unroll 16
            for (int k = 0; k < IN_DIM; ++k)
                accl = fmaf(hsh[jl][k], wlcol[k * HD], accl);
            gls[jl][d] = accl;
        }
    }
    __syncthreads();

    int il = jl, jt = d;
    int i = itile * 32 + il;

    float glv[HD], avv[HD];
#pragma unroll
    for (int dd = 0; dd < HD; ++dd) glv[dd] = gls[il][dd];
    const float* ap = Wak + head * HD;
#pragma unroll
    for (int dd = 0; dd < HD; ++dd) avv[dd] = ap[dd];

    const unsigned char* mrow = mask + ((size_t)(b * N_SZ + i)) * N_SZ;

    float m = -1e30f, l = 0.f;
    float o[HD];
#pragma unroll
    for (int dd = 0; dd < HD; ++dd) o[dd] = 0.f;

    for (int jj = 0; jj < N_SZ / 16; ++jj) {
        int j = jj * 16 + jt;
        const float* r = &grs[j * 18];
        float gj[HD];
#pragma unroll
        for (int e = 0; e < HD / 2; ++e) {
            float2 v = *(const float2*)(r + 2 * e);
            gj[2 * e] = v.x; gj[2 * e + 1] = v.y;
        }

        float s = 0.f;
#pragma unroll
        for (int dd = 0; dd < HD; ++dd) {
            float x = glv[dd] + gj[dd];
            float lr = fmaxf(x, SLOPE * x);
            s = fmaf(avv[dd], lr, s);
        }
        if (mrow[j]) s = -1e30f;

        float mn = fmaxf(m, s);
        float cc = __expf(m - mn);
        float p = __expf(s - mn);
        l = fmaf(l, cc, p);
#pragma unroll
        for (int dd = 0; dd < HD; ++dd)
            o[dd] = fmaf(o[dd], cc, p * gj[dd]);
        m = mn;
    }

#pragma unroll
    for (int off = 1; off < 16; off <<= 1) {
        float mo = __shfl_xor(m, off, 64);
        float lo = __shfl_xor(l, off, 64);
        float mn = fmaxf(m, mo);
        float c1 = __expf(m - mn), c2 = __expf(mo - mn);
        l = l * c1 + lo * c2;
#pragma unroll
        for (int dd = 0; dd < HD; ++dd)
            o[dd] = o[dd] * c1 + __shfl_xor(o[dd], off, 64) * c2;
        m = mn;
    }

    if (jt == 0) {
        float inv = 1.f / l;
        float res[HD];
#pragma unroll
        for (int dd = 0; dd < HD; ++dd)
            res[dd] = fmaxf(o[dd] * inv, 0.f);
        float* op = out + ((size_t)(b * N_SZ + i)) * (NH * HD) + head * HD;
#pragma unroll
        for (int e = 0; e < HD / 4; ++e)
            *(float4*)(op + 4 * e) = *(float4*)(res + 4 * e);
    }
}

extern "C" void kernel_launch(void* const* d_in, const int* in_sizes, int n_in,
                              void* d_out, int out_size, void* d_ws, size_t ws_size,
                              hipStream_t stream) {
    const float* hin = (const float*)d_in[0];
    const unsigned char* mask = (const unsigned char*)d_in[1];
    const float* Wl = (const float*)d_in[2];
    const float* Wr = (const float*)d_in[3];
    const float* Wak = (const float*)d_in[4];
    float* out = (float*)d_out;
    (void)in_sizes; (void)n_in; (void)out_size;

    const size_t need = (size_t)WS_TOT * sizeof(float);   // 2 MB

    if (ws_size >= need && d_ws != nullptr) {
        float* ws = (float*)d_ws;
        float* gl = ws + WS_GL;
        float* gr = ws + WS_GR;
        proj_gemm<<<(B_SZ * N_SZ / PM) * 4, 256, 0, stream>>>(hin, Wl, Wr, gl, gr);
        attn_wave<<<NH * B_SZ * 32, 256, 0, stream>>>(gl, gr, Wak, mask, out);
    } else {
        gatv2_fused<<<NH * B_SZ * (N_SZ / 32), 512, 0, stream>>>(
            hin, mask, Wl, Wr, Wak, out);
    }
}

// Round 16
// 87.070 us; speedup vs baseline: 1.2686x; 1.1155x over previous
//
#include <hip/hip_runtime.h>
#include <hip/hip_bf16.h>

#define B_SZ 4
#define N_SZ 512
#define IN_DIM 128
#define NH 8
#define HD 16
#define SLOPE 0.2f

#define ROWS 32
#define JT   16
#define TPB  512
#define GR_STRIDE 20             // 80 B rows: 16B-aligned b128; jt/jt+8 2-way alias = free
#define GLS_STRIDE 20

typedef float v2f __attribute__((ext_vector_type(2)));

// ws layout (floats): just gl, gr
#define WS_GL 0
#define WS_GR (NH * B_SZ * N_SZ * HD)                    // 262144
#define WS_TOT (2 * WS_GR)

// ---------------- proj as register-tiled GEMM ----------------
#define PM 32
#define PKC 64
#define AT_S 38
#define BT_S 68

__global__ __launch_bounds__(256) void proj_gemm(
    const float* __restrict__ hin, const float* __restrict__ Wl,
    const float* __restrict__ Wr, float* __restrict__ gl, float* __restrict__ gr)
{
    __shared__ float At[PKC * AT_S];
    __shared__ float Bs[PKC * BT_S];

    int rt = blockIdx.x >> 2;
    int ct = blockIdx.x & 3;
    int side = ct >> 1;
    int headbase = (ct & 1) * 4;
    const float* Wsrc = side ? Wr : Wl;
    int rowbase = rt * PM;

    int t = threadIdx.x;
    int ty = t >> 4;
    int tx = t & 15;

    float acc[2][4] = {{0.f,0.f,0.f,0.f},{0.f,0.f,0.f,0.f}};

    for (int kc = 0; kc < IN_DIM; kc += PKC) {
        __syncthreads();
#pragma unroll
        for (int it = 0; it < 2; ++it) {
            int task = it * 256 + t;
            int r = task >> 4, kq = task & 15;
            float4 v = *(const float4*)&hin[(size_t)(rowbase + r) * IN_DIM + kc + kq * 4];
            At[(kq * 4 + 0) * AT_S + r] = v.x;
            At[(kq * 4 + 1) * AT_S + r] = v.y;
            At[(kq * 4 + 2) * AT_S + r] = v.z;
            At[(kq * 4 + 3) * AT_S + r] = v.w;
        }
#pragma unroll
        for (int it = 0; it < 4; ++it) {
            int task = it * 256 + t;
            int k = task >> 4, cc4 = task & 15;
            int head = headbase + (cc4 >> 2);
            int dq = (cc4 & 3) * 4;
            float4 v = *(const float4*)&Wsrc[head * (IN_DIM * HD) + (kc + k) * HD + dq];
            *(float4*)&Bs[k * BT_S + cc4 * 4] = v;
        }
        __syncthreads();

#pragma unroll 16
        for (int k = 0; k < PKC; ++k) {
            float2 a = *(const float2*)&At[k * AT_S + ty * 2];
            float4 b = *(const float4*)&Bs[k * BT_S + tx * 4];
            acc[0][0] = fmaf(a.x, b.x, acc[0][0]);
            acc[0][1] = fmaf(a.x, b.y, acc[0][1]);
            acc[0][2] = fmaf(a.x, b.z, acc[0][2]);
            acc[0][3] = fmaf(a.x, b.w, acc[0][3]);
            acc[1][0] = fmaf(a.y, b.x, acc[1][0]);
            acc[1][1] = fmaf(a.y, b.y, acc[1][1]);
            acc[1][2] = fmaf(a.y, b.z, acc[1][2]);
            acc[1][3] = fmaf(a.y, b.w, acc[1][3]);
        }
    }

    int head = headbase + (tx >> 2);
    int d4 = (tx & 3) * 4;
    float* g = side ? gr : gl;
#pragma unroll
    for (int r = 0; r < 2; ++r) {
        int row = rowbase + ty * 2 + r;
        int b = row >> 9, i = row & (N_SZ - 1);
        float4 v = {acc[r][0], acc[r][1], acc[r][2], acc[r][3]};
        *(float4*)&g[((size_t)(head * B_SZ + b) * N_SZ + i) * HD + d4] = v;
    }
}

// ---------------- attn: block = (hb, itile of 32 rows), full j range (R11 structure) ----------------
// score (minus softmax-invariant per-row const) = 0.6*(a.gr_j) + 0.4*sum_d a_d*|gl_id+gr_jd|
__global__ __launch_bounds__(TPB, 4) void attn_kernel(
    const float* __restrict__ gl, const float* __restrict__ gr,
    const float* __restrict__ Wak, const unsigned char* __restrict__ mask,
    float* __restrict__ out)
{
    __shared__ float grs[N_SZ * GR_STRIDE];     // 40960 B
    __shared__ float gls[ROWS * GLS_STRIDE];    //  2560 B
    __shared__ float crs[N_SZ];                 //  2048 B

    int bid = blockIdx.x;
    int itile = bid & 15;
    int hb = bid >> 4;                 // head*4 + b
    int head = hb >> 2, b = hb & 3;
    int t = threadIdx.x;

    int il = t >> 4;                   // 0..31
    int jt = t & 15;                   // 0..15
    int i = itile * ROWS + il;

    // stage g_r (512 x 16) via float4 (grs rows 16B-aligned)
    const float* grp = gr + (size_t)hb * (N_SZ * HD);
#pragma unroll
    for (int it = 0; it < 4; ++it) {
        int idx4 = it * TPB + t;
        float4 v = ((const float4*)grp)[idx4];
        int j = idx4 >> 2, dq = (idx4 & 3) * 4;
        *(float4*)&grs[j * GR_STRIDE + dq] = v;
    }
    // stage g_l for our 32 rows
    const float* glp = gl + ((size_t)hb * N_SZ + itile * ROWS) * HD;
    {
        int row = t >> 4, d = t & 15;
        gls[row * GLS_STRIDE + d] = glp[t];
    }

    // prefetch mask bits (independent byte loads, one latency hit)
    const unsigned char* mrow = mask + ((size_t)(b * N_SZ + i)) * N_SZ;
    unsigned mbits = 0;
#pragma unroll
    for (int jj = 0; jj < N_SZ / JT; ++jj)
        mbits |= (mrow[jj * JT + jt] ? 1u : 0u) << jj;

    __syncthreads();

    const float* ap = Wak + head * HD;   // uniform -> scalar loads

    // crs[j] = 0.6 * (a . gr_j), one j per thread
    {
        const float* r = &grs[t * GR_STRIDE];
        float acc = 0.f;
#pragma unroll
        for (int dd = 0; dd < HD; ++dd) acc = fmaf(ap[dd], r[dd], acc);
        crs[t] = 0.6f * acc;
    }

    v2f glv[HD / 2], o[HD / 2];
    const float* grow = &gls[il * GLS_STRIDE];
#pragma unroll
    for (int e = 0; e < HD / 2; ++e) glv[e] = *(const v2f*)(grow + 2 * e);
    // NOTE: the 0.6*(a.gl_i) term is a per-row constant -> cancels in softmax; omitted.
#pragma unroll
    for (int e = 0; e < HD / 2; ++e) o[e] = (v2f){0.f, 0.f};

    __syncthreads();                   // crs ready

    float l = 0.f;

#pragma unroll 2
    for (int jj = 0; jj < N_SZ / JT; ++jj) {
        int j = jj * JT + jt;
        const float* r = &grs[j * GR_STRIDE];
        float4 g01 = *(const float4*)(r);
        float4 g23 = *(const float4*)(r + 4);
        float4 g45 = *(const float4*)(r + 8);
        float4 g67 = *(const float4*)(r + 12);
        v2f gj[HD / 2] = {
            (v2f){g01.x, g01.y}, (v2f){g01.z, g01.w},
            (v2f){g23.x, g23.y}, (v2f){g23.z, g23.w},
            (v2f){g45.x, g45.y}, (v2f){g45.z, g45.w},
            (v2f){g67.x, g67.y}, (v2f){g67.z, g67.w}};

        float s0 = 0.f, s1 = 0.f;
#pragma unroll
        for (int e = 0; e < HD / 2; ++e) {       // pk_add + 2 scalar fma (|x| free mod)
            v2f x = glv[e] + gj[e];
            s0 = fmaf(ap[2 * e],     fabsf(x.x), s0);
            s1 = fmaf(ap[2 * e + 1], fabsf(x.y), s1);
        }
        float s = fmaf(0.4f, s0 + s1, crs[j]);
        s = fminf(s, 80.f);
        if (mbits & (1u << jj)) s = -1e30f;

        float p = __expf(s);
        l += p;
        v2f pv = (v2f){p, p};
#pragma unroll
        for (int e = 0; e < HD / 2; ++e)
            o[e] += pv * gj[e];                   // v_pk_fma_f32
    }

    // sum-merge across the 16 jt lanes
#pragma unroll
    for (int off = 1; off < JT; off <<= 1) {
        l += __shfl_xor(l, off, 64);
#pragma unroll
        for (int e = 0; e < HD / 2; ++e) {
            v2f other;
            other.x = __shfl_xor(o[e].x, off, 64);
            other.y = __shfl_xor(o[e].y, off, 64);
            o[e] += other;
        }
    }

    if (jt == 0) {
        float inv = 1.f / l;
        float res[HD];
#pragma unroll
        for (int e = 0; e < HD / 2; ++e) {
            res[2 * e]     = fmaxf(o[e].x * inv, 0.f);
            res[2 * e + 1] = fmaxf(o[e].y * inv, 0.f);
        }
        float* op = out + ((size_t)(b * N_SZ + i)) * (NH * HD) + head * HD;
        *(float4*)op = *(float4*)res;
        *(float4*)(op + 4) = *(float4*)(res + 4);
        *(float4*)(op + 8) = *(float4*)(res + 8);
        *(float4*)(op + 12) = *(float4*)(res + 12);
    }
}

// ---------------- fallback: fused kernel (no workspace) ----------------
__global__ __launch_bounds__(TPB) void gatv2_fused(
    const float* __restrict__ hin, const unsigned char* __restrict__ mask,
    const float* __restrict__ Wl, const float* __restrict__ Wr,
    const float* __restrict__ Wak, float* __restrict__ out)
{
    __shared__ float wrs[IN_DIM * HD];
    __shared__ float hsh[32][IN_DIM + 1];
    __shared__ float grs[N_SZ * 18];
    __shared__ float gls[32][HD];

    int bid = blockIdx.x;
    int itile = bid & 15;
    int hb = bid >> 4;
    int head = hb >> 2, b = hb & 3;
    int t = threadIdx.x;

    int jl = t >> 4;
    int d  = t & 15;

    for (int idx = t; idx < IN_DIM * HD; idx += TPB)
        wrs[idx] = Wr[head * IN_DIM * HD + idx];

    const float* hb_base = hin + (size_t)b * N_SZ * IN_DIM;
    const float* wlcol = Wl + head * IN_DIM * HD + d;

    for (int c = 0; c < N_SZ / 32; ++c) {
        __syncthreads();
        const float* hc = hb_base + (size_t)c * 32 * IN_DIM;
        for (int idx = t; idx < 32 * IN_DIM; idx += TPB)
            hsh[idx >> 7][idx & 127] = hc[idx];
        __syncthreads();

        float acc = 0.f;
#pragma unroll 16
        for (int k = 0; k < IN_DIM; ++k)
            acc = fmaf(hsh[jl][k], wrs[k * HD + d], acc);
        grs[(c * 32 + jl) * 18 + d] = acc;

        if (c == itile) {
            float accl = 0.f;
#pragma unroll 16
            for (int k = 0; k < IN_DIM; ++k)
                accl = fmaf(hsh[jl][k], wlcol[k * HD], accl);
            gls[jl][d] = accl;
        }
    }
    __syncthreads();

    int il = jl, jt = d;
    int i = itile * 32 + il;

    float glv[HD], avv[HD];
#pragma unroll
    for (int dd = 0; dd < HD; ++dd) glv[dd] = gls[il][dd];
    const float* ap = Wak + head * HD;
#pragma unroll
    for (int dd = 0; dd < HD; ++dd) avv[dd] = ap[dd];

    const unsigned char* mrow = mask + ((size_t)(b * N_SZ + i)) * N_SZ;

    float m = -1e30f, l = 0.f;
    float o[HD];
#pragma unroll
    for (int dd = 0; dd < HD; ++dd) o[dd] = 0.f;

    for (int jj = 0; jj < N_SZ / 16; ++jj) {
        int j = jj * 16 + jt;
        const float* r = &grs[j * 18];
        float gj[HD];
#pragma unroll
        for (int e = 0; e < HD / 2; ++e) {
            float2 v = *(const float2*)(r + 2 * e);
            gj[2 * e] = v.x; gj[2 * e + 1] = v.y;
        }

        float s = 0.f;
#pragma unroll
        for (int dd = 0; dd < HD; ++dd) {
            float x = glv[dd] + gj[dd];
            float lr = fmaxf(x, SLOPE * x);
            s = fmaf(avv[dd], lr, s);
        }
        if (mrow[j]) s = -1e30f;

        float mn = fmaxf(m, s);
        float cc = __expf(m - mn);
        float p = __expf(s - mn);
        l = fmaf(l, cc, p);
#pragma unroll
        for (int dd = 0; dd < HD; ++dd)
            o[dd] = fmaf(o[dd], cc, p * gj[dd]);
        m = mn;
    }

#pragma unroll
    for (int off = 1; off < 16; off <<= 1) {
        float mo = __shfl_xor(m, off, 64);
        float lo = __shfl_xor(l, off, 64);
        float mn = fmaxf(m, mo);
        float c1 = __expf(m - mn), c2 = __expf(mo - mn);
        l = l * c1 + lo * c2;
#pragma unroll
        for (int dd = 0; dd < HD; ++dd)
            o[dd] = o[dd] * c1 + __shfl_xor(o[dd], off, 64) * c2;
        m = mn;
    }

    if (jt == 0) {
        float inv = 1.f / l;
        float res[HD];
#pragma unroll
        for (int dd = 0; dd < HD; ++dd)
            res[dd] = fmaxf(o[dd] * inv, 0.f);
        float* op = out + ((size_t)(b * N_SZ + i)) * (NH * HD) + head * HD;
#pragma unroll
        for (int e = 0; e < HD / 4; ++e)
            *(float4*)(op + 4 * e) = *(float4*)(res + 4 * e);
    }
}

extern "C" void kernel_launch(void* const* d_in, const int* in_sizes, int n_in,
                              void* d_out, int out_size, void* d_ws, size_t ws_size,
                              hipStream_t stream) {
    const float* hin = (const float*)d_in[0];
    const unsigned char* mask = (const unsigned char*)d_in[1];
    const float* Wl = (const float*)d_in[2];
    const float* Wr = (const float*)d_in[3];
    const float* Wak = (const float*)d_in[4];
    float* out = (float*)d_out;
    (void)in_sizes; (void)n_in; (void)out_size;

    const size_t need = (size_t)WS_TOT * sizeof(float);   // 2 MB

    if (ws_size >= need && d_ws != nullptr) {
        float* ws = (float*)d_ws;
        float* gl = ws + WS_GL;
        float* gr = ws + WS_GR;
        proj_gemm<<<(B_SZ * N_SZ / PM) * 4, 256, 0, stream>>>(hin, Wl, Wr, gl, gr);
        attn_kernel<<<NH * B_SZ * (N_SZ / ROWS), TPB, 0, stream>>>(
            gl, gr, Wak, mask, out);
    } else {
        gatv2_fused<<<NH * B_SZ * (N_SZ / 32), TPB, 0, stream>>>(
            hin, mask, Wl, Wr, Wak, out);
    }
}